// Round 13
// baseline (3711.114 us; speedup 1.0000x reference)
//
#include <hip/hip_runtime.h>

typedef _Float16 f16;
typedef _Float16 f16x8 __attribute__((ext_vector_type(8)));
typedef float f32x4 __attribute__((ext_vector_type(4)));

// async global->LDS, 16B per lane; LDS dest must be linear (base + lane*16).
__device__ __forceinline__ void gload_lds16(const void* g, void* l) {
  __builtin_amdgcn_global_load_lds(
      (const __attribute__((address_space(1))) void*)g,
      (__attribute__((address_space(3))) void*)l, 16, 0, 0);
}

__device__ __forceinline__ float act_apply(float x, int id) {
  switch (id) {
    case 0: return fmaxf(x, 0.0f);
    case 1: return 1.0f / (1.0f + __expf(-x));
    case 2: return tanhf(x);
    case 3: return x >= 0.0f ? x : 0.1f * x;
    default: return 1.0507009873554805f *
                    (x > 0.0f ? x : 1.6732632423543772f * expm1f(x));
  }
}

// ============================================================================
// GEMM body (proven r9 core + swizzled epilogue), shared via macro so the
// control (4 blocks/CU) and occupancy-test (5 blocks/CU) kernels are
// byte-identical in source. 128x128 tile, BK=32, 2-deep dbuf, __syncthreads
// drain, zero-conflict swizzled LDS, r9 2D-chunked XCD mapping.
// ============================================================================
#define GEMM128_BODY(FINAL)                                                   \
  __shared__ f16 lA[2][128 * 32];                                             \
  __shared__ f16 lB[2][128 * 32];                                             \
                                                                              \
  const int tid  = (int)threadIdx.x;                                          \
  const int lane = tid & 63;                                                  \
  const int wid  = tid >> 6;                                                  \
  const int wr   = (wid >> 1) * 64;                                           \
  const int wc   = (wid & 1) * 64;                                            \
                                                                              \
  const int nbc = N >> 7;                                                     \
  const int b   = (int)blockIdx.x;                                            \
  const int x   = b & 7;                                                      \
  const int r   = b >> 3;                                                     \
  int brow, bcol;                                                             \
  if (nbc >= 32) {                                                            \
    brow = ((x >> 1) * 16 + (r & 15)) << 7;                                   \
    bcol = ((x & 1) * (nbc >> 1) + (r >> 4)) << 7;                            \
  } else {                                                                    \
    brow = (x * 8 + (r & 7)) << 7;                                            \
    bcol = (r >> 3) << 7;                                                     \
  }                                                                           \
                                                                              \
  const int d0 = tid << 4;                                                    \
  const int d1 = d0 + 4096;                                                   \
  const int s0 = d0 ^ (((d0 >> 7) & 7) << 4);                                 \
  const int s1 = d1 ^ (((d1 >> 7) & 7) << 4);                                 \
  const int r0 = s0 >> 6, c0 = (s0 >> 4) & 3;                                 \
  const int r1 = s1 >> 6, c1 = (s1 >> 4) & 3;                                 \
                                                                              \
  const f16* pA0 = A + (long)(brow + r0) * K + c0 * 8;                        \
  const f16* pA1 = A + (long)(brow + r1) * K + c1 * 8;                        \
  const f16* pB0 = W + (long)(bcol + r0) * K + c0 * 8;                        \
  const f16* pB1 = W + (long)(bcol + r1) * K + c1 * 8;                        \
  const int e0 = tid << 3;                                                    \
  const int e1 = e0 + 2048;                                                   \
                                                                              \
  const int fr = lane & 15;                                                   \
  const int kb = lane >> 4;                                                   \
  const int xorv = ((fr >> 1) & 7) << 4;                                      \
                                                                              \
  int offA[4], offB[4];                                                       \
  _Pragma("unroll")                                                           \
  for (int m = 0; m < 4; ++m)                                                 \
    offA[m] = (((wr + m * 16 + fr) << 6) + (kb << 4)) ^ xorv;                 \
  _Pragma("unroll")                                                           \
  for (int n = 0; n < 4; ++n)                                                 \
    offB[n] = (((wc + n * 16 + fr) << 6) + (kb << 4)) ^ xorv;                 \
                                                                              \
  f32x4 acc[4][4];                                                            \
  _Pragma("unroll")                                                           \
  for (int m = 0; m < 4; ++m)                                                 \
    _Pragma("unroll")                                                         \
    for (int n = 0; n < 4; ++n) acc[m][n] = (f32x4){0.f, 0.f, 0.f, 0.f};      \
                                                                              \
  const int nt = K >> 5;                                                      \
  int buf = 0;                                                                \
                                                                              \
  gload_lds16(pA0, &lA[0][e0]);                                               \
  gload_lds16(pA1, &lA[0][e1]);                                               \
  gload_lds16(pB0, &lB[0][e0]);                                               \
  gload_lds16(pB1, &lB[0][e1]);                                               \
  __syncthreads();                                                            \
                                                                              \
  for (int t = 0; t < nt; ++t) {                                              \
    if (t + 1 < nt) {                                                         \
      const long kk = (long)(t + 1) << 5;                                     \
      gload_lds16(pA0 + kk, &lA[buf ^ 1][e0]);                                \
      gload_lds16(pA1 + kk, &lA[buf ^ 1][e1]);                                \
      gload_lds16(pB0 + kk, &lB[buf ^ 1][e0]);                                \
      gload_lds16(pB1 + kk, &lB[buf ^ 1][e1]);                                \
    }                                                                         \
    const char* bA = (const char*)&lA[buf][0];                                \
    const char* bB = (const char*)&lB[buf][0];                                \
    f16x8 af[4], bf[4];                                                       \
    _Pragma("unroll")                                                         \
    for (int m = 0; m < 4; ++m) af[m] = *(const f16x8*)(bA + offA[m]);        \
    _Pragma("unroll")                                                         \
    for (int n = 0; n < 4; ++n) bf[n] = *(const f16x8*)(bB + offB[n]);        \
    _Pragma("unroll")                                                         \
    for (int m = 0; m < 4; ++m)                                               \
      _Pragma("unroll")                                                       \
      for (int n = 0; n < 4; ++n)                                             \
        acc[m][n] = __builtin_amdgcn_mfma_f32_16x16x32_f16(af[m], bf[n],      \
                                                           acc[m][n], 0, 0, 0);\
    if (t + 1 < nt) {                                                         \
      __syncthreads();                                                        \
      buf ^= 1;                                                               \
    }                                                                         \
  }                                                                           \
                                                                              \
  const int r4 = (lane >> 4) << 2;                                            \
  if (!(FINAL)) {                                                             \
    __syncthreads();                                                          \
    char* eb = (char*)((wid < 2) ? &lA[wid][0] : &lB[wid - 2][0]);            \
    _Pragma("unroll")                                                         \
    for (int n = 0; n < 4; ++n) {                                             \
      const int gcol = bcol + wc + n * 16 + fr;                               \
      const float bv = bias[gcol];                                            \
      const int id   = ids[gcol];                                             \
      _Pragma("unroll")                                                       \
      for (int m = 0; m < 4; ++m)                                             \
        _Pragma("unroll")                                                     \
        for (int i = 0; i < 4; ++i) {                                         \
          const float y = act_apply(acc[m][n][i] * Sa + bv, id);              \
          const int w = ((m * 16 + r4 + i) * 64 + n * 16 + fr) * 2;           \
          *(f16*)(eb + (w ^ (((w >> 7) & 7) << 4))) = (f16)(y * invSn);       \
        }                                                                     \
    }                                                                         \
    __syncthreads();                                                          \
    f16* outp = (f16*)outv;                                                   \
    _Pragma("unroll")                                                         \
    for (int j = 0; j < 8; ++j) {                                             \
      const int lrow = j * 8 + (lane >> 3);                                   \
      const int rd = lrow * 128 + (lane & 7) * 16;                            \
      const f16x8 v = *(const f16x8*)(eb + (rd ^ (((rd >> 7) & 7) << 4)));    \
      *(f16x8*)&outp[(long)(brow + wr + lrow) * N + bcol + wc +               \
                     (lane & 7) * 8] = v;                                     \
    }                                                                         \
  } else {                                                                    \
    _Pragma("unroll")                                                         \
    for (int n = 0; n < 4; ++n) {                                             \
      const int gcol = bcol + wc + n * 16 + fr;                               \
      const float bv = bias[gcol];                                            \
      const int id   = ids[gcol];                                             \
      _Pragma("unroll")                                                       \
      for (int m = 0; m < 4; ++m) {                                           \
        const int grow = brow + wr + m * 16 + r4;                             \
        _Pragma("unroll")                                                     \
        for (int i = 0; i < 4; ++i) {                                         \
          const float y = act_apply(acc[m][n][i] * Sa + bv, id);              \
          ((float*)outv)[(long)(grow + i) * N + gcol] = y;                    \
        }                                                                     \
      }                                                                       \
    }                                                                         \
  }

// control: 4 blocks/CU (r9 exact)
template <bool FINAL>
__global__ __launch_bounds__(256, 4)
void gemm128(const f16* __restrict__ A, const f16* __restrict__ W,
             const float* __restrict__ bias, const int* __restrict__ ids,
             float Sa, float invSn, void* __restrict__ outv,
             int M, int N, int K) {
  GEMM128_BODY(FINAL)
}

// occupancy test: 5 blocks/CU (LDS 5 x 32KiB = 160KiB exactly; VGPR 56 << 102)
__global__ __launch_bounds__(256, 5)
void gemm128o(const f16* __restrict__ A, const f16* __restrict__ W,
              const float* __restrict__ bias, const int* __restrict__ ids,
              float Sa, float invSn, void* __restrict__ outv,
              int M, int N, int K) {
  GEMM128_BODY(false)
}

__global__ void cvt_f32_to_f16(const float* __restrict__ in, f16* __restrict__ out,
                               float scale, int n) {
  int i = ((int)blockIdx.x * 256 + (int)threadIdx.x) * 8;
  const int stride = (int)gridDim.x * 256 * 8;
  for (; i < n; i += stride) {
    const float4 v0 = *(const float4*)(in + i);
    const float4 v1 = *(const float4*)(in + i + 4);
    f16x8 h;
    h[0] = (f16)(v0.x * scale); h[1] = (f16)(v0.y * scale);
    h[2] = (f16)(v0.z * scale); h[3] = (f16)(v0.w * scale);
    h[4] = (f16)(v1.x * scale); h[5] = (f16)(v1.y * scale);
    h[6] = (f16)(v1.z * scale); h[7] = (f16)(v1.w * scale);
    *(f16x8*)(out + i) = h;
  }
}

extern "C" void kernel_launch(void* const* d_in, const int* in_sizes, int n_in,
                              void* d_out, int out_size, void* d_ws, size_t ws_size,
                              hipStream_t stream) {
  (void)in_sizes; (void)n_in; (void)out_size; (void)ws_size;
  const int M = 8192, IND = 2048, HID = 4096, OUTD = 2048;
  const float* x = (const float*)d_in[0];

  f16* actA = (f16*)d_ws;
  f16* actB = actA + (size_t)M * HID;
  f16* wbuf = actB + (size_t)M * HID;

  // static per-layer activation scales (powers of 2, exact)
  const float S[6] = {1.f, 16.f, 512.f, 16384.f, 262144.f, 8388608.f};
  const int Ks[6] = {IND, HID, HID, HID, HID, HID};
  const int Ns[6] = {HID, HID, HID, HID, HID, OUTD};

  cvt_f32_to_f16<<<2048, 256, 0, stream>>>(x, actA, 1.0f, M * IND);

  f16* cur = actA;
  f16* nxt = actB;
  for (int i = 0; i < 6; ++i) {
    const int K = Ks[i], N = Ns[i];
    const float* w  = (const float*)d_in[1 + 3 * i];
    const float* bs = (const float*)d_in[2 + 3 * i];
    const int* id   = (const int*)d_in[3 + 3 * i];

    cvt_f32_to_f16<<<2048, 256, 0, stream>>>(w, wbuf, 1.0f, N * K);

    const int nblk = (M >> 7) * (N >> 7);
    // A/B fork: layers 1,2 -> gemm128o (5 blocks/CU); 0,3,4 -> gemm128
    // control (4 blocks/CU); layer 5 -> gemm128<true>.
    // Layers 1,2 vs 3,4 are identical 8192x4096x4096 shapes.
    if (i == 1 || i == 2) {
      gemm128o<<<nblk, 256, 0, stream>>>(
          cur, wbuf, bs, id, S[i], 1.0f / S[i + 1], nxt, M, N, K);
      f16* t = cur; cur = nxt; nxt = t;
    } else if (i < 5) {
      gemm128<false><<<nblk, 256, 0, stream>>>(
          cur, wbuf, bs, id, S[i], 1.0f / S[i + 1], nxt, M, N, K);
      f16* t = cur; cur = nxt; nxt = t;
    } else {
      gemm128<true><<<nblk, 256, 0, stream>>>(
          cur, wbuf, bs, id, S[i], 1.0f, d_out, M, N, K);
    }
  }
}

// Round 14
// 1931.670 us; speedup vs baseline: 1.9212x; 1.9212x over previous
//
#include <hip/hip_runtime.h>

typedef _Float16 f16;
typedef _Float16 f16x8 __attribute__((ext_vector_type(8)));
typedef float f32x4 __attribute__((ext_vector_type(4)));

// async global->LDS, 16B per lane; LDS dest must be linear (base + lane*16).
__device__ __forceinline__ void gload_lds16(const void* g, void* l) {
  __builtin_amdgcn_global_load_lds(
      (const __attribute__((address_space(1))) void*)g,
      (__attribute__((address_space(3))) void*)l, 16, 0, 0);
}

__device__ __forceinline__ float act_apply(float x, int id) {
  switch (id) {
    case 0: return fmaxf(x, 0.0f);
    case 1: return 1.0f / (1.0f + __expf(-x));
    case 2: return tanhf(x);
    case 3: return x >= 0.0f ? x : 0.1f * x;
    default: return 1.0507009873554805f *
                    (x > 0.0f ? x : 1.6732632423543772f * expm1f(x));
  }
}

// ============================================================================
// gemm128 — best-measured configuration (r9 exact, 1928us total):
//   128x128 tile, BK=32, 2-deep dbuf, __syncthreads drain, 4 blocks/CU
//   (VGPR 56, no spill; 5 blocks/CU proven to spill catastrophically in r13),
//   zero-conflict sigma-swizzled LDS (staging pre-swizzled source + swizzled
//   ds_read), r9 2D-chunked XCD mapping (map-optimal 256MB FETCH floor),
//   sigma-swizzled LDS-transpose f16 epilogue (WRITE = 64MB ideal).
// ============================================================================
template <bool FINAL>
__global__ __launch_bounds__(256, 4)
void gemm128(const f16* __restrict__ A, const f16* __restrict__ W,
             const float* __restrict__ bias, const int* __restrict__ ids,
             float Sa, float invSn, void* __restrict__ outv,
             int M, int N, int K) {
  __shared__ f16 lA[2][128 * 32];   // 2 x 8 KiB
  __shared__ f16 lB[2][128 * 32];   // 2 x 8 KiB  (32 KiB total)

  const int tid  = (int)threadIdx.x;
  const int lane = tid & 63;
  const int wid  = tid >> 6;   // 0..3
  const int wr   = (wid >> 1) * 64;
  const int wc   = (wid & 1) * 64;

  // 2D-chunked XCD mapping: XCD x owns a 16x16 (or 8x16) block chunk,
  // row-fastest inner order. Global fetch floor: 2xA + 4xW = 256MB (optimal
  // for square chunking; measured ~400MB incl. L2-lifetime effects).
  const int nbc = N >> 7;
  const int b   = (int)blockIdx.x;
  const int x   = b & 7;
  const int r   = b >> 3;
  int brow, bcol;
  if (nbc >= 32) {
    brow = ((x >> 1) * 16 + (r & 15)) << 7;
    bcol = ((x & 1) * (nbc >> 1) + (r >> 4)) << 7;
  } else {
    brow = (x * 8 + (r & 7)) << 7;
    bcol = (r >> 3) << 7;
  }

  // staging: pre-swizzled global source, linear LDS dest (rule: gload_lds
  // writes base+lane*16; swizzle must be applied to the SOURCE permutation
  // and the READ address with the same involution).
  const int d0 = tid << 4;
  const int d1 = d0 + 4096;
  const int s0 = d0 ^ (((d0 >> 7) & 7) << 4);
  const int s1 = d1 ^ (((d1 >> 7) & 7) << 4);
  const int r0 = s0 >> 6, c0 = (s0 >> 4) & 3;
  const int r1 = s1 >> 6, c1 = (s1 >> 4) & 3;

  const f16* pA0 = A + (long)(brow + r0) * K + c0 * 8;
  const f16* pA1 = A + (long)(brow + r1) * K + c1 * 8;
  const f16* pB0 = W + (long)(bcol + r0) * K + c0 * 8;
  const f16* pB1 = W + (long)(bcol + r1) * K + c1 * 8;
  const int e0 = tid << 3;
  const int e1 = e0 + 2048;

  const int fr = lane & 15;
  const int kb = lane >> 4;
  const int xorv = ((fr >> 1) & 7) << 4;

  int offA[4], offB[4];
#pragma unroll
  for (int m = 0; m < 4; ++m)
    offA[m] = (((wr + m * 16 + fr) << 6) + (kb << 4)) ^ xorv;
#pragma unroll
  for (int n = 0; n < 4; ++n)
    offB[n] = (((wc + n * 16 + fr) << 6) + (kb << 4)) ^ xorv;

  f32x4 acc[4][4];
#pragma unroll
  for (int m = 0; m < 4; ++m)
#pragma unroll
    for (int n = 0; n < 4; ++n) acc[m][n] = (f32x4){0.f, 0.f, 0.f, 0.f};

  const int nt = K >> 5;
  int buf = 0;

  gload_lds16(pA0, &lA[0][e0]);
  gload_lds16(pA1, &lA[0][e1]);
  gload_lds16(pB0, &lB[0][e0]);
  gload_lds16(pB1, &lB[0][e1]);
  __syncthreads();   // compiler drains vmcnt before s_barrier

  for (int t = 0; t < nt; ++t) {
    if (t + 1 < nt) {
      const long kk = (long)(t + 1) << 5;
      gload_lds16(pA0 + kk, &lA[buf ^ 1][e0]);
      gload_lds16(pA1 + kk, &lA[buf ^ 1][e1]);
      gload_lds16(pB0 + kk, &lB[buf ^ 1][e0]);
      gload_lds16(pB1 + kk, &lB[buf ^ 1][e1]);
    }
    const char* bA = (const char*)&lA[buf][0];
    const char* bB = (const char*)&lB[buf][0];
    f16x8 af[4], bf[4];
#pragma unroll
    for (int m = 0; m < 4; ++m) af[m] = *(const f16x8*)(bA + offA[m]);
#pragma unroll
    for (int n = 0; n < 4; ++n) bf[n] = *(const f16x8*)(bB + offB[n]);
#pragma unroll
    for (int m = 0; m < 4; ++m)
#pragma unroll
      for (int n = 0; n < 4; ++n)
        acc[m][n] = __builtin_amdgcn_mfma_f32_16x16x32_f16(af[m], bf[n],
                                                           acc[m][n], 0, 0, 0);
    if (t + 1 < nt) {
      __syncthreads();
      buf ^= 1;
    }
  }

  // D layout: row = (lane>>4)*4 + reg, col = lane&15  (m89-verified)
  const int r4 = (lane >> 4) << 2;

  if (!FINAL) {
    // sigma-swizzled LDS-transpose epilogue: coalesced 16B f16 stores,
    // zero bank conflicts (verified r10: SQ_LDS_BANK_CONFLICT 1.05e6 -> 0).
    __syncthreads();   // staging LDS dead; reuse as 4 x 8KB per-wave tiles
    char* eb = (char*)((wid < 2) ? &lA[wid][0] : &lB[wid - 2][0]);
#pragma unroll
    for (int n = 0; n < 4; ++n) {
      const int gcol = bcol + wc + n * 16 + fr;
      const float bv = bias[gcol];
      const int id   = ids[gcol];
#pragma unroll
      for (int m = 0; m < 4; ++m)
#pragma unroll
        for (int i = 0; i < 4; ++i) {
          const float y = act_apply(acc[m][n][i] * Sa + bv, id);
          const int w = ((m * 16 + r4 + i) * 64 + n * 16 + fr) * 2;
          *(f16*)(eb + (w ^ (((w >> 7) & 7) << 4))) = (f16)(y * invSn);
        }
    }
    __syncthreads();
    f16* outp = (f16*)outv;
#pragma unroll
    for (int j = 0; j < 8; ++j) {
      const int lrow = j * 8 + (lane >> 3);
      const int rd = lrow * 128 + (lane & 7) * 16;
      const f16x8 v = *(const f16x8*)(eb + (rd ^ (((rd >> 7) & 7) << 4)));
      *(f16x8*)&outp[(long)(brow + wr + lrow) * N + bcol + wc + (lane & 7) * 8] = v;
    }
  } else {
    // final layer: fp32 output (one layer; 4x64B segments per wave-store)
#pragma unroll
    for (int n = 0; n < 4; ++n) {
      const int gcol = bcol + wc + n * 16 + fr;
      const float bv = bias[gcol];
      const int id   = ids[gcol];
#pragma unroll
      for (int m = 0; m < 4; ++m) {
        const int grow = brow + wr + m * 16 + r4;
#pragma unroll
        for (int i = 0; i < 4; ++i) {
          const float y = act_apply(acc[m][n][i] * Sa + bv, id);
          ((float*)outv)[(long)(grow + i) * N + gcol] = y;
        }
      }
    }
  }
}

__global__ void cvt_f32_to_f16(const float* __restrict__ in, f16* __restrict__ out,
                               float scale, int n) {
  int i = ((int)blockIdx.x * 256 + (int)threadIdx.x) * 8;
  const int stride = (int)gridDim.x * 256 * 8;
  for (; i < n; i += stride) {
    const float4 v0 = *(const float4*)(in + i);
    const float4 v1 = *(const float4*)(in + i + 4);
    f16x8 h;
    h[0] = (f16)(v0.x * scale); h[1] = (f16)(v0.y * scale);
    h[2] = (f16)(v0.z * scale); h[3] = (f16)(v0.w * scale);
    h[4] = (f16)(v1.x * scale); h[5] = (f16)(v1.y * scale);
    h[6] = (f16)(v1.z * scale); h[7] = (f16)(v1.w * scale);
    *(f16x8*)(out + i) = h;
  }
}

extern "C" void kernel_launch(void* const* d_in, const int* in_sizes, int n_in,
                              void* d_out, int out_size, void* d_ws, size_t ws_size,
                              hipStream_t stream) {
  (void)in_sizes; (void)n_in; (void)out_size; (void)ws_size;
  const int M = 8192, IND = 2048, HID = 4096, OUTD = 2048;
  const float* x = (const float*)d_in[0];

  // workspace: actA (64MB f16) | actB (64MB f16) | wbuf (32MB f16)
  f16* actA = (f16*)d_ws;
  f16* actB = actA + (size_t)M * HID;
  f16* wbuf = actB + (size_t)M * HID;

  // static per-layer activation scales (powers of 2, exact): h_i stored as h/S[i]
  const float S[6] = {1.f, 16.f, 512.f, 16384.f, 262144.f, 8388608.f};
  const int Ks[6] = {IND, HID, HID, HID, HID, HID};
  const int Ns[6] = {HID, HID, HID, HID, HID, OUTD};

  cvt_f32_to_f16<<<2048, 256, 0, stream>>>(x, actA, 1.0f, M * IND);

  f16* cur = actA;
  f16* nxt = actB;
  for (int i = 0; i < 6; ++i) {
    const int K = Ks[i], N = Ns[i];
    const float* w  = (const float*)d_in[1 + 3 * i];
    const float* bs = (const float*)d_in[2 + 3 * i];
    const int* id   = (const int*)d_in[3 + 3 * i];

    cvt_f32_to_f16<<<2048, 256, 0, stream>>>(w, wbuf, 1.0f, N * K);

    const int nblk = (M >> 7) * (N >> 7);
    if (i < 5) {
      gemm128<false><<<nblk, 256, 0, stream>>>(
          cur, wbuf, bs, id, S[i], 1.0f / S[i + 1], nxt, M, N, K);
      f16* t = cur; cur = nxt; nxt = t;
    } else {
      gemm128<true><<<nblk, 256, 0, stream>>>(
          cur, wbuf, bs, id, S[i], 1.0f, d_out, M, N, K);
    }
  }
}